// Round 7
// baseline (327.545 us; speedup 1.0000x reference)
//
#include <hip/hip_runtime.h>
#include <cstdint>
#include <cstddef>

#define F_ALPHA 0.5f
#define THRESH  0.5f
#define EPS8    1e-8f
#define EPS7    1e-7f
#define MAXM    64
#define CCLS    21
#define NBUCK   1024   // 32x32 Morton buckets
#define MAXBLK  512    // cap on number of 256-prior chunks

// Morton interleave of 5-bit (bx, by) -> 10-bit bucket
__device__ __forceinline__ unsigned morton_bucket(float4 d)
{
    float cx = 0.5f * (d.x + d.z);
    float cy = 0.5f * (d.y + d.w);
    int bx = min(max((int)(cx * 32.0f), 0), 31);
    int by = min(max((int)(cy * 32.0f), 0), 31);
    unsigned r = 0;
    #pragma unroll
    for (int i = 0; i < 5; i++)
        r |= (((unsigned)(bx >> i) & 1u) << (2 * i))
           | (((unsigned)(by >> i) & 1u) << (2 * i + 1));
    return r;
}

// ---------------------------------------------------------------------------
// histo: per-block LDS histogram -> hist_part[block][NBUCK]. No global
// atomics, no preceding memset launch.
// ---------------------------------------------------------------------------
__global__ __launch_bounds__(256)
void histo_kernel(const float4* __restrict__ dbox, int* __restrict__ hist_part, int P)
{
    __shared__ int lh[NBUCK];
    const int t = threadIdx.x;
    for (int i = t; i < NBUCK; i += 256) lh[i] = 0;
    __syncthreads();
    int p = blockIdx.x * 256 + t;
    if (p < P) atomicAdd(&lh[morton_bucket(dbox[p])], 1);
    __syncthreads();
    for (int i = t; i < NBUCK; i += 256)
        hist_part[(size_t)blockIdx.x * NBUCK + i] = lh[i];
}

// scan: sum partials per bucket + exclusive prefix (1 block, 1024 threads)
__global__ __launch_bounds__(1024)
void scan_kernel(const int* __restrict__ hist_part, int* __restrict__ offs, int nparts)
{
    __shared__ int tmp[NBUCK];
    int t = threadIdx.x;
    int h = 0;
    for (int j = 0; j < nparts; j++) h += hist_part[(size_t)j * NBUCK + t];
    int v = h;
    tmp[t] = v;
    __syncthreads();
    for (int d = 1; d < NBUCK; d <<= 1) {
        int u = (t >= d) ? tmp[t - d] : 0;
        __syncthreads();
        v += u;
        tmp[t] = v;
        __syncthreads();
    }
    offs[t] = v - h;    // exclusive prefix
}

__global__ __launch_bounds__(256)
void scatter_kernel(const float4* __restrict__ dbox, int* __restrict__ offs,
                    float4* __restrict__ sbox, int* __restrict__ sperm, int P)
{
    int p = blockIdx.x * 256 + threadIdx.x;
    if (p < P) {
        float4 d = dbox[p];
        int pos = atomicAdd(&offs[morton_bucket(d)], 1);
        sbox[pos] = d;
        sperm[pos] = p;
    }
}

// per-chunk (256 sorted priors) bounding extent
__global__ __launch_bounds__(256)
void extent_kernel(const float4* __restrict__ sbox, float4* __restrict__ bext, int P)
{
    __shared__ float red[4][4];
    const int t = threadIdx.x;
    const int p = blockIdx.x * 256 + t;
    const bool valid = (p < P);
    float4 d = valid ? sbox[p] : make_float4(0.f, 0.f, 0.f, 0.f);
    float mnx = valid ? d.x : 1e30f, mny = valid ? d.y : 1e30f;
    float mxz = valid ? d.z : -1e30f, mxw = valid ? d.w : -1e30f;
    for (int o = 32; o > 0; o >>= 1) {
        mnx = fminf(mnx, __shfl_xor(mnx, o, 64));
        mny = fminf(mny, __shfl_xor(mny, o, 64));
        mxz = fmaxf(mxz, __shfl_xor(mxz, o, 64));
        mxw = fmaxf(mxw, __shfl_xor(mxw, o, 64));
    }
    const int wv = t >> 6, lane = t & 63;
    if (lane == 0) {
        red[wv][0] = mnx; red[wv][1] = mny; red[wv][2] = mxz; red[wv][3] = mxw;
    }
    __syncthreads();
    if (t == 0) {
        float4 e;
        e.x = fminf(fminf(red[0][0], red[1][0]), fminf(red[2][0], red[3][0]));
        e.y = fminf(fminf(red[0][1], red[1][1]), fminf(red[2][1], red[3][1]));
        e.z = fmaxf(fmaxf(red[0][2], red[1][2]), fmaxf(red[2][2], red[3][2]));
        e.w = fmaxf(fmaxf(red[0][3], red[1][3]), fmaxf(red[2][3], red[3][3]));
        bext[blockIdx.x] = e;
    }
}

// ---------------------------------------------------------------------------
// bt: per-prior best GT. Morton-gated, no in-loop reductions, 1 barrier.
// ---------------------------------------------------------------------------
__global__ __launch_bounds__(256)
void bt_kernel(const float4* __restrict__ sbox, const int* __restrict__ sperm,
               const float4* __restrict__ gt, const float4* __restrict__ bext,
               unsigned char* __restrict__ match, int P, int M)
{
    __shared__ float4 tb[MAXM];
    __shared__ float  tarea[MAXM];
    __shared__ unsigned amask_lo, amask_hi;

    const int t = threadIdx.x;
    const int b = blockIdx.y;
    const int p0 = blockIdx.x * 256;
    const int p = p0 + t;
    const bool valid = (p < P);

    const float4 e = bext[blockIdx.x];

    bool act = false;
    if (t < M) {
        float4 g = gt[(size_t)b * M + t];
        tb[t] = g;
        tarea[t] = (g.z - g.x) * (g.w - g.y);
        act = (g.x < e.z) && (g.z > e.x) && (g.y < e.w) && (g.w > e.y);
    }
    unsigned long long bal = __ballot(act);   // t<M lanes are all in wave 0
    if (t == 0) { amask_lo = (unsigned)bal; amask_hi = (unsigned)(bal >> 32); }

    float4 d = valid ? sbox[p] : make_float4(2.f, 2.f, 2.f, 2.f);
    const unsigned orig = valid ? (unsigned)sperm[p] : 0u;
    const float darea = (d.z - d.x) * (d.w - d.y);
    __syncthreads();
    const unsigned long long amask = ((unsigned long long)amask_hi << 32) | amask_lo;

    float best = -1.0f;   // strict > => first active m on ties; skipped rows have iou=0
    int   bm = 0;
    for (int m = 0; m < M; m++) {
        if (!((amask >> m) & 1)) continue;     // block-uniform scalar skip
        float4 g = tb[m];
        float lx = fmaxf(d.x, g.x), ly = fmaxf(d.y, g.y);
        float rx = fminf(d.z, g.z), ry = fminf(d.w, g.w);
        float ww = fmaxf(rx - lx, 0.f), hh = fmaxf(ry - ly, 0.f);
        float inter = ww * hh;
        // fast rcp: feeds compares only; bit-identical expression in bp_kernel
        float iou = inter * __builtin_amdgcn_rcpf(darea + tarea[m] - inter);
        if (iou > best) { best = iou; bm = m; }
    }

    if (valid) {
        unsigned char code = (unsigned char)((best >= THRESH ? 0x40 : 0) | bm);
        match[(size_t)b * P + orig] = code;
    }
}

// ---------------------------------------------------------------------------
// bp: per-GT best prior. One block per (m, b), extent-gated chunks,
// single hoisted reduction, plain store (no atomics, no init pass).
// ---------------------------------------------------------------------------
__global__ __launch_bounds__(256)
void bp_kernel(const float4* __restrict__ sbox, const int* __restrict__ sperm,
               const float4* __restrict__ gt, const float4* __restrict__ bext,
               unsigned long long* __restrict__ bpkey, int P, int M, int nblk)
{
    __shared__ float4 ext[MAXBLK];
    __shared__ unsigned long long wred[4];

    const int t = threadIdx.x;
    const int m = blockIdx.x;
    const int b = blockIdx.y;

    for (int i = t; i < nblk; i += 256) ext[i] = bext[i];
    const float4 g = gt[(size_t)b * M + m];
    const float garea = (g.z - g.x) * (g.w - g.y);
    __syncthreads();

    // fallback key = (iou=0, p=0): all-zero column argmax -> index 0
    unsigned long long key = 0x00000000FFFFFFFFull;

    for (int c = 0; c < nblk; c++) {
        float4 e = ext[c];
        if (g.x >= e.z || g.z <= e.x || g.y >= e.w || g.w <= e.y) continue;
        int p = c * 256 + t;
        if (p >= P) continue;
        float4 d = sbox[p];
        float lx = fmaxf(d.x, g.x), ly = fmaxf(d.y, g.y);
        float rx = fminf(d.z, g.z), ry = fminf(d.w, g.w);
        float ww = fmaxf(rx - lx, 0.f), hh = fmaxf(ry - ly, 0.f);
        float inter = ww * hh;
        float darea = (d.z - d.x) * (d.w - d.y);
        float iou = inter * __builtin_amdgcn_rcpf(darea + garea - inter);
        if (iou > 0.0f) {
            unsigned orig = (unsigned)sperm[p];
            unsigned long long k = ((unsigned long long)__float_as_uint(iou) << 32)
                                 | (unsigned long long)(0xFFFFFFFFu - orig);
            if (k > key) key = k;
        }
    }

    for (int o = 32; o > 0; o >>= 1) {
        unsigned long long other = __shfl_xor(key, o, 64);
        if (other > key) key = other;
    }
    const int wv = t >> 6, lane = t & 63;
    if (lane == 0) wred[wv] = key;
    __syncthreads();
    if (t == 0) {
        unsigned long long k01 = wred[0] > wred[1] ? wred[0] : wred[1];
        unsigned long long k23 = wred[2] > wred[3] ? wred[2] : wred[3];
        bpkey[(size_t)b * M + m] = k01 > k23 ? k01 : k23;
    }
}

// ---------------------------------------------------------------------------
// loss: focal on every anchor + GIoU on positives + fused force-match.
// conf staged direct-to-LDS via global_load_lds width=16 (no VGPR roundtrip).
// ---------------------------------------------------------------------------
__global__ __launch_bounds__(256)
void loss_kernel(const float4* __restrict__ locp,
                 const float*  __restrict__ conf,
                 const float4* __restrict__ dbox,
                 const float4* __restrict__ gt,
                 const int*    __restrict__ gtl,
                 const unsigned long long* __restrict__ bpkey,
                 const unsigned char* __restrict__ match,
                 double* __restrict__ partS,
                 int*    __restrict__ partC,
                 int P, int M)
{
    __shared__ float    scf[256 * CCLS];   // 21504 B = 1344 float4
    __shared__ float4   tb[MAXM];
    __shared__ int      tl[MAXM];
    __shared__ unsigned bpp[MAXM];
    __shared__ double   sv[4];
    __shared__ int      sc[4];

    const int t = threadIdx.x;
    const int b = blockIdx.y;
    const int p0 = blockIdx.x * 256;
    const int p = p0 + t;

    // ---- stage conf tile first (async DMA flows while we load tb/tl/bpp) ----
    const int cnt = min(256, P - p0);
    const float* src = conf + ((size_t)b * P + p0) * CCLS;
    if (cnt == 256 && (((uintptr_t)src & 15) == 0)) {
        const float4* s4 = (const float4*)src;
        float4* l4 = (float4*)scf;
        #pragma unroll
        for (int i = 0; i < 5; i++) {   // 5*256 = 1280 of 1344
            int gdx = i * 256 + t;
            __builtin_amdgcn_global_load_lds(
                (const __attribute__((address_space(1))) void*)(s4 + gdx),
                (__attribute__((address_space(3))) void*)(l4 + gdx),
                16, 0, 0);
        }
        if (t < 64) {                   // remainder 64 float4s: wave 0 only (uniform)
            int gdx = 1280 + t;
            __builtin_amdgcn_global_load_lds(
                (const __attribute__((address_space(1))) void*)(s4 + gdx),
                (__attribute__((address_space(3))) void*)(l4 + gdx),
                16, 0, 0);
        }
    } else {                            // block-uniform tail path
        int nf = cnt * CCLS;
        for (int i = t; i < nf; i += 256) scf[i] = src[i];
    }

    if (t < M) {
        tb[t] = gt[(size_t)b * M + t];
        tl[t] = gtl[(size_t)b * M + t];
        bpp[t] = 0xFFFFFFFFu - (unsigned)(bpkey[(size_t)b * M + t] & 0xFFFFFFFFull);
    }
    __syncthreads();                    // drains vmcnt incl. LDS-DMA

    double acc = 0.0;
    int cnt_pos = 0;
    if (p < P) {
        unsigned char code = match[(size_t)b * P + p];
        int  idx = code & 0x3F;
        bool pos = (code & 0x40) != 0;
        for (int j = 0; j < M; j++) {   // force-match: j ascending, last wins
            if (bpp[j] == (unsigned)p) { idx = j; pos = true; }
        }
        int lbl = pos ? tl[idx] : 0;

        const float* x = scf + t * CCLS;
        float mx = -1e30f;
        #pragma unroll
        for (int c = 0; c < CCLS; c++) mx = fmaxf(mx, x[c]);
        float sum = 0.f;
        #pragma unroll
        for (int c = 0; c < CCLS; c++) sum += expf(x[c] - mx);
        float ce = (mx + logf(sum)) - x[lbl];
        float pt = expf(-ce);
        float om = 1.f - pt;
        acc = (double)(F_ALPHA * om * sqrtf(om) * ce);

        if (pos) {
            cnt_pos = 1;
            float4 d = dbox[p];
            float dw = d.z - d.x, dh = d.w - d.y;
            float dcx = d.x + dw * 0.5f, dcy = d.y + dh * 0.5f;
            float4 g = tb[idx];
            float gw = g.z - g.x, gh = g.w - g.y;
            float gcx = g.x + gw * 0.5f, gcy = g.y + gh * 0.5f;
            float ex = (gcx - dcx) / (dw + EPS8);
            float ey = (gcy - dcy) / (dh + EPS8);
            float ew = logf(gw / (dw + EPS8) + EPS8);
            float eh = logf(gh / (dh + EPS8) + EPS8);
            float tcx = ex * dw + dcx, tcy = ey * dh + dcy;
            float tw = expf(ew) * dw,  th = expf(eh) * dh;
            float t0 = tcx - tw * 0.5f, t1 = tcy - th * 0.5f;
            float t2 = tcx + tw * 0.5f, t3 = tcy + th * 0.5f;
            float4 l = locp[(size_t)b * P + p];
            float pcx = l.x * dw + dcx, pcy = l.y * dh + dcy;
            float pw = expf(l.z) * dw,  ph = expf(l.w) * dh;
            float q0 = pcx - pw * 0.5f, q1 = pcy - ph * 0.5f;
            float q2 = pcx + pw * 0.5f, q3 = pcy + ph * 0.5f;
            float ix0 = fmaxf(q0, t0), iy0 = fmaxf(q1, t1);
            float ix1 = fminf(q2, t2), iy1 = fminf(q3, t3);
            float iw = fmaxf(ix1 - ix0, 0.f), ih = fmaxf(iy1 - iy0, 0.f);
            float inter = iw * ih;
            float pa = (q2 - q0) * (q3 - q1);
            float ta = (t2 - t0) * (t3 - t1);
            float uni = pa + ta - inter;
            float iou = inter / (uni + EPS7);
            float e0 = fminf(q0, t0), e1 = fminf(q1, t1);
            float e2 = fmaxf(q2, t2), e3 = fmaxf(q3, t3);
            float ewd = fmaxf(e2 - e0, 0.f), ehd = fmaxf(e3 - e1, 0.f);
            float encl = ewd * ehd;
            float giou = iou - (encl - uni) / (encl + EPS7);
            acc += (double)(1.f - giou);
        }
    }

    for (int o = 32; o > 0; o >>= 1) {
        acc += __shfl_down(acc, o, 64);
        cnt_pos += __shfl_down(cnt_pos, o, 64);
    }
    int w = t >> 6, lane = t & 63;
    if (lane == 0) { sv[w] = acc; sc[w] = cnt_pos; }
    __syncthreads();
    if (t == 0) {
        int slot = blockIdx.y * gridDim.x + blockIdx.x;
        partS[slot] = sv[0] + sv[1] + sv[2] + sv[3];
        partC[slot] = sc[0] + sc[1] + sc[2] + sc[3];
    }
}

__global__ __launch_bounds__(256)
void final_kernel(const double* __restrict__ partS,
                  const int*    __restrict__ partC,
                  float* __restrict__ out, int n)
{
    __shared__ double sv[4];
    __shared__ long long sc[4];
    const int t = threadIdx.x;
    double a = 0.0; long long c = 0;
    for (int i = t; i < n; i += 256) { a += partS[i]; c += partC[i]; }
    for (int o = 32; o > 0; o >>= 1) {
        a += __shfl_down(a, o, 64);
        c += __shfl_down(c, o, 64);
    }
    int w = t >> 6, lane = t & 63;
    if (lane == 0) { sv[w] = a; sc[w] = c; }
    __syncthreads();
    if (t == 0) {
        double s = sv[0] + sv[1] + sv[2] + sv[3];
        long long np = sc[0] + sc[1] + sc[2] + sc[3];
        out[0] = (np == 0) ? 0.0f : (float)(s / (double)np);
    }
}

// ---------------------------------------------------------------------------
extern "C" void kernel_launch(void* const* d_in, const int* in_sizes, int n_in,
                              void* d_out, int out_size, void* d_ws, size_t ws_size,
                              hipStream_t stream)
{
    const float* locp = (const float*)d_in[0];   // [B,P,4]
    const float* conf = (const float*)d_in[1];   // [B,P,C]
    const float* dbox = (const float*)d_in[2];   // [P,4]
    const float* gt   = (const float*)d_in[3];   // [B,M,4]
    const int*   gtl  = (const int*)d_in[4];     // [B,M]

    const int P  = in_sizes[2] / 4;
    const long long BP = (long long)in_sizes[0] / 4;
    const int B  = (int)(BP / P);
    const int M  = in_sizes[4] / B;

    const int nblk = (P + 255) / 256;
    const int nPart = nblk * B;

    // ws layout (descending alignment):
    char* ws = (char*)d_ws;
    size_t off = 0;
    float4* sbox = (float4*)(ws + off);           off += (size_t)P * 16;
    float4* bext = (float4*)(ws + off);           off += (size_t)nblk * 16;
    unsigned long long* bpkey = (unsigned long long*)(ws + off); off += (size_t)B * M * 8;
    double* partS = (double*)(ws + off);          off += (size_t)nPart * 8;
    int* hist_part = (int*)(ws + off);            off += (size_t)nblk * NBUCK * 4;
    int* offs  = (int*)(ws + off);                off += (size_t)NBUCK * 4;
    int* sperm = (int*)(ws + off);                off += (size_t)P * 4;
    int* partC = (int*)(ws + off);                off += (size_t)nPart * 4;
    unsigned char* match = (unsigned char*)(ws + off);

    dim3 grid(nblk, B);
    histo_kernel<<<nblk, 256, 0, stream>>>((const float4*)dbox, hist_part, P);
    scan_kernel<<<1, NBUCK, 0, stream>>>(hist_part, offs, nblk);
    scatter_kernel<<<nblk, 256, 0, stream>>>((const float4*)dbox, offs, sbox, sperm, P);
    extent_kernel<<<nblk, 256, 0, stream>>>(sbox, bext, P);
    bt_kernel<<<grid, 256, 0, stream>>>(sbox, sperm, (const float4*)gt, bext,
                                        match, P, M);
    bp_kernel<<<dim3(M, B), 256, 0, stream>>>(sbox, sperm, (const float4*)gt, bext,
                                              bpkey, P, M, nblk);
    loss_kernel<<<grid, 256, 0, stream>>>((const float4*)locp, conf,
                                          (const float4*)dbox, (const float4*)gt,
                                          gtl, bpkey, match, partS, partC, P, M);
    final_kernel<<<1, 256, 0, stream>>>(partS, partC, (float*)d_out, nPart);
}